// Round 4
// baseline (173.527 us; speedup 1.0000x reference)
//
#include <hip/hip_runtime.h>
#include <math.h>

#define BROWS 512
#define SLEN  8192
#define NT    1024             // threads per block (16 waves)
#define CHUNK 8                // contiguous positions per thread
#define NWRD  (SLEN / 32)      // 256 mask words per row
#define MWRD  (NWRD + 2)       // +1 guard word each side

// distance (capped; >5 -> 99) to nearest set bit within +/-5 of position t
__device__ __forceinline__ int win_dist(const unsigned int* __restrict__ M, int t) {
    int sI = t + 27;                   // (t-5) + 32-bit guard offset
    int w  = sI >> 5;
    int off = sI & 31;
    unsigned long long val =
        ((unsigned long long)M[w] | ((unsigned long long)M[w + 1] << 32)) >> off;
    unsigned int win = (unsigned int)val & 0x7FFu;   // bit5 == position t
    if (win & 32u) return 0;
    unsigned int dn = win & 31u;          // bits 0..4 = t-5..t-1 (bit i -> dist 5-i)
    unsigned int up = (win >> 6) & 31u;   // bits 0..4 = t+1..t+5 (bit j -> dist j+1)
    int d = 99;
    if (dn) d = 5 - (31 - __clz((int)dn));
    if (up) { int du = __ffs((int)up); if (du < d) d = du; }
    return d;
}

__device__ __forceinline__ float decay_pow(int d) {
    return (d == 1) ? 0.7f : (d == 2) ? 0.49f : (d == 3) ? 0.343f
         : (d == 4) ? 0.2401f : 0.16807f;
}

__global__ __launch_bounds__(NT, 8) void row_loss_kernel(
    const float* __restrict__ logits, const int* __restrict__ labels,
    double* __restrict__ psum, unsigned int* __restrict__ pcnt)
{
    __shared__ unsigned int  s_m[4][MWRD];      // ~4.1 KB  masks: t2, p2, t3, p3
    __shared__ unsigned int  s_wave[16];
    __shared__ unsigned int  s_flags;
    __shared__ double        s_red[16];
    __shared__ int           s_redc[16];

    const int row  = blockIdx.x;
    const int tid  = threadIdx.x;
    const int lane = tid & 63;
    const int wid  = tid >> 6;
    const int base = tid * CHUNK;

    // zero guard words only (interior fully written below)
    if (tid < 4) { s_m[tid][0] = 0u; s_m[tid][MWRD - 1] = 0u; }
    if (tid == 4) s_flags = 0u;

    const float4* lg4 = (const float4*)logits + (size_t)row * SLEN + base;
    const int4*   lb4 = (const int4*)(labels + (size_t)row * SLEN + base);

    // ---- Phase 1: thread-contiguous loads; ce/pk stay in registers ----
    int4 la0 = lb4[0], la1 = lb4[1];
    int labs[8] = {la0.x, la0.y, la0.z, la0.w, la1.x, la1.y, la1.z, la1.w};

    float ce[8];
    unsigned long long pkw = 0ull;   // 8 bytes: pred(2b)|lab(2b)|valid(1b)
    unsigned int mt2 = 0, mp2 = 0, mt3 = 0, mp3 = 0;
    unsigned int summary = 0;        // bit0 pm, bit1 tm, bit2 any_valid
    int cnt = 0;

    #pragma unroll
    for (int b = 0; b < 2; ++b) {
        float4 q[4];
        #pragma unroll
        for (int j = 0; j < 4; ++j) q[j] = lg4[b * 4 + j];
        #pragma unroll
        for (int j = 0; j < 4; ++j) {
            const int i = b * 4 + j;
            float4 v = q[j];
            int lab = labs[i];
            float m01 = fmaxf(v.x, v.y), m23 = fmaxf(v.z, v.w);
            float best = fmaxf(m01, m23);
            int pred = (best == v.x) ? 0 : (best == v.y) ? 1 : (best == v.z) ? 2 : 3;
            bool valid = (lab != -100);
            cnt += valid ? 1 : 0;
            int l = valid ? (lab & 3) : 0;
            float se = __expf(v.x - best) + __expf(v.y - best) +
                       __expf(v.z - best) + __expf(v.w - best);
            float lse = best + __logf(se);
            float xl = (l == 0) ? v.x : (l == 1) ? v.y : (l == 2) ? v.z : v.w;
            float wc = (l >= 2) ? 30.0f : 1.0f;
            ce[i] = valid ? (lse - xl) * wc : 0.0f;
            pkw |= (unsigned long long)(pred | (l << 2) | (valid ? 16 : 0)) << (8 * i);
            if (pred == 2) mp2 |= 1u << i;
            if (pred == 3) mp3 |= 1u << i;
            if (valid && l == 2) mt2 |= 1u << i;
            if (valid && l == 3) mt3 |= 1u << i;
            if (valid) summary = 4u | (unsigned)(pred & 1) | ((unsigned)(l & 1) << 1);
        }
    }

    // ---- Publish masks (4-lane shfl combine -> one word per 4 lanes) ----
    {
        int sh = (tid & 3) * 8;
        unsigned int w0 = mt2 << sh, w1 = mp2 << sh, w2 = mt3 << sh, w3 = mp3 << sh;
        w0 |= __shfl_xor(w0, 1); w0 |= __shfl_xor(w0, 2);
        w1 |= __shfl_xor(w1, 1); w1 |= __shfl_xor(w1, 2);
        w2 |= __shfl_xor(w2, 1); w2 |= __shfl_xor(w2, 2);
        w3 |= __shfl_xor(w3, 1); w3 |= __shfl_xor(w3, 2);
        if ((tid & 3) == 0) {
            int wi = 1 + (tid >> 2);
            s_m[0][wi] = w0; s_m[1][wi] = w1; s_m[2][wi] = w2; s_m[3][wi] = w3;
        }
    }
    {   // row-wide has-any flags: wave OR-reduce, one LDS atomic per wave
        unsigned int fl = (mt2 ? 1u : 0u) | (mp2 ? 2u : 0u) |
                          (mt3 ? 4u : 0u) | (mp3 ? 8u : 0u);
        #pragma unroll
        for (int s = 32; s > 0; s >>= 1) fl |= __shfl_xor(fl, s);
        if (lane == 0 && fl) atomicOr(&s_flags, fl);
    }

    // ---- intra-wave fill-forward scan of chunk summaries ----
    unsigned int inc = summary;
    #pragma unroll
    for (int st = 1; st < 64; st <<= 1) {
        unsigned int o = __shfl_up(inc, st);
        if (lane >= st && !(inc & 4u)) inc = o;
    }
    unsigned int exc = __shfl_up(inc, 1);
    if (lane == 0) exc = 0u;
    if (lane == 63) s_wave[wid] = inc;
    __syncthreads();   // B: masks + flags + wave summaries visible

    // ---- redundant inter-wave scan (every wave, no extra barrier) ----
    unsigned int wv = (lane < 16) ? s_wave[lane] : 0u;
    #pragma unroll
    for (int st = 1; st < 16; st <<= 1) {
        unsigned int o = __shfl_up(wv, st);
        if (lane >= st && !(wv & 4u)) wv = o;
    }
    unsigned int wpre = __shfl(wv, (wid > 0) ? (wid - 1) : 0);
    if (wid == 0) wpre = 0u;

    unsigned int pre = (exc & 4u) ? exc : wpre;
    int pm = (int)(pre & 1u), tm = (int)((pre >> 1) & 1u);
    const unsigned int flags = s_flags;
    const bool hasT2 = flags & 1u, hasP2 = flags & 2u;
    const bool hasT3 = flags & 4u, hasP3 = flags & 8u;

    // ---- Phase 3: carry replay + window multipliers (all inputs in regs) ----
    float acc = 0.0f;
    #pragma unroll
    for (int i = 0; i < CHUNK; ++i) {
        int t = base + i;
        unsigned int pk = (unsigned int)(pkw >> (8 * i)) & 31u;
        int pred = pk & 3, l = (pk >> 2) & 3;
        bool valid = (pk & 16) != 0;
        float m = 1.0f;
        if (valid) {
            bool bad = (pred == 2 && pm == 0) || (pred == 3 && pm == 1);
            if (bad) m *= 100.0f;
            bool good = (l == 2 && tm == 1 && pred == 2) ||
                        (l == 3 && tm == 0 && pred == 3);
            if (good) m *= 0.1f;
            pm = pred & 1;
            tm = l & 1;
        }
        if (pred >= 2) {                       // predicted-switch multiplier
            bool has = (pred == 2) ? hasT2 : hasT3;
            if (!has) m *= 20.0f;
            else {
                int d = win_dist(s_m[(pred - 2) << 1], t);
                m *= (d == 0) ? 0.1f : (d <= 5) ? decay_pow(d) : 10.0f;
            }
        }
        if (valid && l >= 2) {                 // true-switch multiplier
            bool has = (l == 2) ? hasP2 : hasP3;
            if (!has) m *= 3.0f;
            else if (win_dist(s_m[1 + ((l - 2) << 1)], t) > 5) m *= 2.0f;
        }
        acc += ce[i] * m;
    }

    // ---- Reduce to per-row partial ----
    double dacc = (double)acc;
    #pragma unroll
    for (int o = 32; o > 0; o >>= 1) {
        dacc += __shfl_down(dacc, o);
        cnt  += __shfl_down(cnt, o);
    }
    if (lane == 0) { s_red[wid] = dacc; s_redc[wid] = cnt; }
    __syncthreads();   // D
    if (tid == 0) {
        double tot = 0.0; unsigned int c = 0;
        #pragma unroll
        for (int i = 0; i < 16; ++i) { tot += s_red[i]; c += (unsigned int)s_redc[i]; }
        psum[row] = tot;
        pcnt[row] = c;
    }
}

__global__ __launch_bounds__(512) void finalize_kernel(
    const double* __restrict__ psum, const unsigned int* __restrict__ pcnt,
    float* __restrict__ out)
{
    __shared__ double       sd[8];
    __shared__ unsigned int sc[8];
    int tid = threadIdx.x, lane = tid & 63, wid = tid >> 6;
    double v = psum[tid];
    unsigned int c = pcnt[tid];
    #pragma unroll
    for (int o = 32; o > 0; o >>= 1) {
        v += __shfl_down(v, o);
        c += __shfl_down(c, o);
    }
    if (lane == 0) { sd[wid] = v; sc[wid] = c; }
    __syncthreads();
    if (tid == 0) {
        double t = 0.0; unsigned int cc = 0;
        #pragma unroll
        for (int i = 0; i < 8; ++i) { t += sd[i]; cc += sc[i]; }
        double d = (cc > 0u) ? (double)cc : 1.0;
        out[0] = (float)(t / d);
    }
}

extern "C" void kernel_launch(void* const* d_in, const int* in_sizes, int n_in,
                              void* d_out, int out_size, void* d_ws, size_t ws_size,
                              hipStream_t stream) {
    const float* logits = (const float*)d_in[0];
    const int*   labels = (const int*)d_in[1];
    float* out = (float*)d_out;
    double* psum = (double*)d_ws;
    unsigned int* pcnt = (unsigned int*)(psum + BROWS);

    row_loss_kernel<<<BROWS, NT, 0, stream>>>(logits, labels, psum, pcnt);
    finalize_kernel<<<1, 512, 0, stream>>>(psum, pcnt, out);
}

// Round 5
// 121.655 us; speedup vs baseline: 1.4264x; 1.4264x over previous
//
#include <hip/hip_runtime.h>
#include <math.h>

#define BROWS 512
#define SLEN  8192
#define NT    1024             // threads per block (16 waves)
#define CHUNK 8                // contiguous positions per thread
#define NWRD  (SLEN / 32)      // 256 mask words per row
#define MWRD  (NWRD + 2)       // +1 guard word each side

// distance (capped; >5 -> 99) to nearest set bit within +/-5 of position t
__device__ __forceinline__ int win_dist(const unsigned int* __restrict__ M, int t) {
    int sI = t + 27;                   // (t-5) + 32-bit guard offset
    int w  = sI >> 5;
    int off = sI & 31;
    unsigned long long val =
        ((unsigned long long)M[w] | ((unsigned long long)M[w + 1] << 32)) >> off;
    unsigned int win = (unsigned int)val & 0x7FFu;   // bit5 == position t
    if (win & 32u) return 0;
    unsigned int dn = win & 31u;          // bits 0..4 = t-5..t-1 (bit i -> dist 5-i)
    unsigned int up = (win >> 6) & 31u;   // bits 0..4 = t+1..t+5 (bit j -> dist j+1)
    int d = 99;
    if (dn) d = 5 - (31 - __clz((int)dn));
    if (up) { int du = __ffs((int)up); if (du < d) d = du; }
    return d;
}

__device__ __forceinline__ float decay_pow(int d) {
    return (d == 1) ? 0.7f : (d == 2) ? 0.49f : (d == 3) ? 0.343f
         : (d == 4) ? 0.2401f : 0.16807f;
}

// ---- per-position phase-1 macro: argmax + CE + pack (all named scalars) ----
#define P1(i, v, lab, cev) {                                                  \
    float m01 = fmaxf((v).x, (v).y), m23 = fmaxf((v).z, (v).w);               \
    float best = fmaxf(m01, m23);                                             \
    int pred = (best == (v).x) ? 0 : (best == (v).y) ? 1                      \
             : (best == (v).z) ? 2 : 3;                                       \
    bool valid = ((lab) != -100);                                             \
    cnt += valid ? 1 : 0;                                                     \
    int l = valid ? ((lab) & 3) : 0;                                          \
    float se = __expf((v).x - best) + __expf((v).y - best) +                  \
               __expf((v).z - best) + __expf((v).w - best);                   \
    float lse = best + __logf(se);                                            \
    float xl = (l == 0) ? (v).x : (l == 1) ? (v).y : (l == 2) ? (v).z : (v).w;\
    float wc = (l >= 2) ? 30.0f : 1.0f;                                       \
    cev = valid ? (lse - xl) * wc : 0.0f;                                     \
    pkw |= (unsigned long long)(unsigned)(pred | (l << 2) | (valid ? 16 : 0)) \
           << (8 * (i));                                                      \
    if (pred == 2) mp2 |= 1u << (i);                                          \
    if (pred == 3) mp3 |= 1u << (i);                                          \
    if (valid && l == 2) mt2 |= 1u << (i);                                    \
    if (valid && l == 3) mt3 |= 1u << (i);                                    \
    if (valid) summary = 4u | (unsigned)(pred & 1) | ((unsigned)(l & 1) << 1);\
}

// ---- per-position phase-3 macro: carry replay + window multipliers ----
#define P3(i, cev) {                                                          \
    int t = base + (i);                                                       \
    unsigned int pk = (unsigned int)(pkw >> (8 * (i))) & 31u;                 \
    int pred = pk & 3, l = (pk >> 2) & 3;                                     \
    bool valid = (pk & 16) != 0;                                              \
    float m = 1.0f;                                                           \
    if (valid) {                                                              \
        bool bad = (pred == 2 && pm == 0) || (pred == 3 && pm == 1);          \
        if (bad) m *= 100.0f;                                                 \
        bool good = (l == 2 && tm == 1 && pred == 2) ||                       \
                    (l == 3 && tm == 0 && pred == 3);                         \
        if (good) m *= 0.1f;                                                  \
        pm = pred & 1;                                                        \
        tm = l & 1;                                                           \
    }                                                                         \
    if (pred >= 2) {                                                          \
        bool has = (pred == 2) ? hasT2 : hasT3;                               \
        if (!has) m *= 20.0f;                                                 \
        else {                                                                \
            int d = win_dist(s_m[(pred - 2) << 1], t);                        \
            m *= (d == 0) ? 0.1f : (d <= 5) ? decay_pow(d) : 10.0f;           \
        }                                                                     \
    }                                                                         \
    if (valid && l >= 2) {                                                    \
        bool has = (l == 2) ? hasP2 : hasP3;                                  \
        if (!has) m *= 3.0f;                                                  \
        else if (win_dist(s_m[1 + ((l - 2) << 1)], t) > 5) m *= 2.0f;         \
    }                                                                         \
    acc += (cev) * m;                                                         \
}

__global__ __launch_bounds__(NT, 4) void row_loss_kernel(
    const float* __restrict__ logits, const int* __restrict__ labels,
    double* __restrict__ psum, unsigned int* __restrict__ pcnt)
{
    __shared__ unsigned int  s_m[4][MWRD];      // ~4.1 KB  masks: t2, p2, t3, p3
    __shared__ unsigned int  s_wave[16];
    __shared__ unsigned int  s_flags;
    __shared__ double        s_red[16];
    __shared__ int           s_redc[16];

    const int row  = blockIdx.x;
    const int tid  = threadIdx.x;
    const int lane = tid & 63;
    const int wid  = tid >> 6;
    const int base = tid * CHUNK;

    // zero guard words only (interior fully written below)
    if (tid < 4) { s_m[tid][0] = 0u; s_m[tid][MWRD - 1] = 0u; }
    if (tid == 4) s_flags = 0u;

    const float4* lg4 = (const float4*)logits + (size_t)row * SLEN + base;
    const int4*   lb4 = (const int4*)(labels + (size_t)row * SLEN + base);

    // ---- Phase 1: thread-contiguous loads; everything in named scalars ----
    int4 la0 = lb4[0], la1 = lb4[1];
    float4 q0 = lg4[0], q1 = lg4[1], q2 = lg4[2], q3 = lg4[3];
    float4 q4 = lg4[4], q5 = lg4[5], q6 = lg4[6], q7 = lg4[7];

    unsigned long long pkw = 0ull;   // 8 bytes: pred(2b)|lab(2b)|valid(1b)
    unsigned int mt2 = 0, mp2 = 0, mt3 = 0, mp3 = 0;
    unsigned int summary = 0;        // bit0 pm, bit1 tm, bit2 any_valid
    int cnt = 0;
    float ce0, ce1, ce2, ce3, ce4, ce5, ce6, ce7;

    P1(0, q0, la0.x, ce0); P1(1, q1, la0.y, ce1);
    P1(2, q2, la0.z, ce2); P1(3, q3, la0.w, ce3);
    P1(4, q4, la1.x, ce4); P1(5, q5, la1.y, ce5);
    P1(6, q6, la1.z, ce6); P1(7, q7, la1.w, ce7);

    // ---- Publish masks (4-lane shfl combine -> one word per 4 lanes) ----
    {
        int sh = (tid & 3) * 8;
        unsigned int w0 = mt2 << sh, w1 = mp2 << sh, w2 = mt3 << sh, w3 = mp3 << sh;
        w0 |= __shfl_xor(w0, 1); w0 |= __shfl_xor(w0, 2);
        w1 |= __shfl_xor(w1, 1); w1 |= __shfl_xor(w1, 2);
        w2 |= __shfl_xor(w2, 1); w2 |= __shfl_xor(w2, 2);
        w3 |= __shfl_xor(w3, 1); w3 |= __shfl_xor(w3, 2);
        if ((tid & 3) == 0) {
            int wi = 1 + (tid >> 2);
            s_m[0][wi] = w0; s_m[1][wi] = w1; s_m[2][wi] = w2; s_m[3][wi] = w3;
        }
    }
    {   // row-wide has-any flags: wave OR-reduce, one LDS atomic per wave
        unsigned int fl = (mt2 ? 1u : 0u) | (mp2 ? 2u : 0u) |
                          (mt3 ? 4u : 0u) | (mp3 ? 8u : 0u);
        #pragma unroll
        for (int s = 32; s > 0; s >>= 1) fl |= __shfl_xor(fl, s);
        if (lane == 0 && fl) atomicOr(&s_flags, fl);
    }

    // ---- intra-wave fill-forward scan of chunk summaries ----
    unsigned int inc = summary;
    #pragma unroll
    for (int st = 1; st < 64; st <<= 1) {
        unsigned int o = __shfl_up(inc, st);
        if (lane >= st && !(inc & 4u)) inc = o;
    }
    unsigned int exc = __shfl_up(inc, 1);
    if (lane == 0) exc = 0u;
    if (lane == 63) s_wave[wid] = inc;
    __syncthreads();   // B: masks + flags + wave summaries visible

    // ---- redundant inter-wave scan (every wave, no extra barrier) ----
    unsigned int wv = (lane < 16) ? s_wave[lane] : 0u;
    #pragma unroll
    for (int st = 1; st < 16; st <<= 1) {
        unsigned int o = __shfl_up(wv, st);
        if (lane >= st && !(wv & 4u)) wv = o;
    }
    unsigned int wpre = __shfl(wv, (wid > 0) ? (wid - 1) : 0);
    if (wid == 0) wpre = 0u;

    unsigned int pre = (exc & 4u) ? exc : wpre;
    int pm = (int)(pre & 1u), tm = (int)((pre >> 1) & 1u);
    const unsigned int flags = s_flags;
    const bool hasT2 = flags & 1u, hasP2 = flags & 2u;
    const bool hasT3 = flags & 4u, hasP3 = flags & 8u;

    // ---- Phase 3: carry replay + window multipliers (all inputs in regs) ----
    float acc = 0.0f;
    P3(0, ce0); P3(1, ce1); P3(2, ce2); P3(3, ce3);
    P3(4, ce4); P3(5, ce5); P3(6, ce6); P3(7, ce7);

    // ---- Reduce to per-row partial ----
    double dacc = (double)acc;
    #pragma unroll
    for (int o = 32; o > 0; o >>= 1) {
        dacc += __shfl_down(dacc, o);
        cnt  += __shfl_down(cnt, o);
    }
    if (lane == 0) { s_red[wid] = dacc; s_redc[wid] = cnt; }
    __syncthreads();   // D
    if (tid == 0) {
        double tot = 0.0; unsigned int c = 0;
        #pragma unroll
        for (int i = 0; i < 16; ++i) { tot += s_red[i]; c += (unsigned int)s_redc[i]; }
        psum[row] = tot;
        pcnt[row] = c;
    }
}

__global__ __launch_bounds__(512) void finalize_kernel(
    const double* __restrict__ psum, const unsigned int* __restrict__ pcnt,
    float* __restrict__ out)
{
    __shared__ double       sd[8];
    __shared__ unsigned int sc[8];
    int tid = threadIdx.x, lane = tid & 63, wid = tid >> 6;
    double v = psum[tid];
    unsigned int c = pcnt[tid];
    #pragma unroll
    for (int o = 32; o > 0; o >>= 1) {
        v += __shfl_down(v, o);
        c += __shfl_down(c, o);
    }
    if (lane == 0) { sd[wid] = v; sc[wid] = c; }
    __syncthreads();
    if (tid == 0) {
        double t = 0.0; unsigned int cc = 0;
        #pragma unroll
        for (int i = 0; i < 8; ++i) { t += sd[i]; cc += sc[i]; }
        double d = (cc > 0u) ? (double)cc : 1.0;
        out[0] = (float)(t / d);
    }
}

extern "C" void kernel_launch(void* const* d_in, const int* in_sizes, int n_in,
                              void* d_out, int out_size, void* d_ws, size_t ws_size,
                              hipStream_t stream) {
    const float* logits = (const float*)d_in[0];
    const int*   labels = (const int*)d_in[1];
    float* out = (float*)d_out;
    double* psum = (double*)d_ws;
    unsigned int* pcnt = (unsigned int*)(psum + BROWS);

    row_loss_kernel<<<BROWS, NT, 0, stream>>>(logits, labels, psum, pcnt);
    finalize_kernel<<<1, 512, 0, stream>>>(psum, pcnt, out);
}